// Round 4
// baseline (75.731 us; speedup 1.0000x reference)
//
#include <hip/hip_runtime.h>

typedef float f32x4 __attribute__((ext_vector_type(4)));
typedef short s16x4 __attribute__((ext_vector_type(4)));
typedef short s16x8 __attribute__((ext_vector_type(8)));

#define LOG2E 1.4426950408889634f

// ---- bf16 helpers (bit-level, RNE) ----
__device__ __forceinline__ short f2bf(float f) {
  unsigned u = __float_as_uint(f);
  unsigned r = (u + 0x7fffu + ((u >> 16) & 1u)) >> 16;
  return (short)r;
}
__device__ __forceinline__ float bf2f(short s) {
  return __uint_as_float(((unsigned)(unsigned short)s) << 16);
}

// 16x16x16 bf16. D: col(lane&15)=B-idx, row(4g+reg)=A-idx  [HW-verified]
__device__ __forceinline__ f32x4 mfma16(s16x4 a, s16x4 b, f32x4 c) {
  return __builtin_amdgcn_mfma_f32_16x16x16bf16_1k(a, b, c, 0, 0, 0);
}
// 16x16x32 bf16 (gfx950). Same C/D layout. kappa-matched A/B (g,e)->g*8+e.
__device__ __forceinline__ f32x4 mfma32(s16x8 a, s16x8 b, f32x4 c) {
  return __builtin_amdgcn_mfma_f32_16x16x32_bf16(a, b, c, 0, 0, 0);
}

// async global->LDS, 16B/lane: HW writes lane i at (uniform dst)+i*16.
__device__ __forceinline__ void gl_lds16(const void* gp, void* sp) {
  __builtin_amdgcn_global_load_lds(
      (__attribute__((address_space(1))) void*)const_cast<void*>(gp),
      (__attribute__((address_space(3))) void*)sp, 16, 0, 0);
}

// ============================================================
// Kernel 0: split W^T into bf16 hi/lo.  wt[n][c], n: 0-63 q, 64-127 k, 128-191 v
// ============================================================
__global__ __launch_bounds__(256) void prep_w(
    const float* __restrict__ Wq, const float* __restrict__ Wk, const float* __restrict__ Wv,
    short* __restrict__ wt_hi, short* __restrict__ wt_lo) {
  int idx = blockIdx.x * 256 + threadIdx.x;   // 192*1024 total
  int n = idx >> 10;
  int c = idx & 1023;
  const float* W = (n < 64) ? Wq : ((n < 128) ? Wk : Wv);
  float v = W[c * 64 + (n & 63)];
  short hi = f2bf(v);
  short lo = f2bf(v - bf2f(hi));
  wt_hi[idx] = hi;
  wt_lo[idx] = lo;
}

// ============================================================
// Kernel 1: QKV projection — distance-2 gl_lds pipeline (T3+T4).
// grid 256 x 512 thr. BM=32 tokens, BK=64, 16 K-steps, TRIPLE-buffer LDS
// (3 x 48KB = 144KB). All staging via global_load_lds: W bf16 (pre-swizzled
// src), x raw f32 (pre-swizzled src; bf16 hi/lo split done in-register by
// consumers, 4x dup). Counted s_waitcnt vmcnt(12/6/0) + raw s_barrier:
// stage(s+2) issued at body s, never drained to 0 in the main loop.
// Buffer layout (shorts): whi[192][64]@0, wlo[128][64]@12288, xf32[32][64]@20480.
// Chunk swizzle: W phys8 = logical ^ (row&7); x phys4 = logical ^ (row&15).
// ============================================================
__global__ __launch_bounds__(512, 2) void proj_qkv(
    const float* __restrict__ x,
    const short* __restrict__ wt_hi, const short* __restrict__ wt_lo,
    const float* __restrict__ bq, const float* __restrict__ bk, const float* __restrict__ bv,
    short* __restrict__ q_hi, short* __restrict__ q_lo,
    short* __restrict__ k_hi, short* __restrict__ k_lo,
    short* __restrict__ v_t) {
  const int tid = threadIdx.x;
  const int lane = tid & 63;
  const int wv = tid >> 6;       // 0..7
  const int col = lane & 15;
  const int g = lane >> 4;       // 0..3
  const int mg = wv >> 2;        // 0..1
  const int ng = wv & 3;         // 0..3
  const int tokbase = blockIdx.x * 32;

  __shared__ short lds[3][24576];   // 3 x 48KB = 144KB

  // compute-side row indices (step-invariant)
  const int arow = mg * 16 + col;        // x row 0..31
  const int qrow = ng * 16 + col;        // whi/wlo rows 0..63
  const int krow = 64 + ng * 16 + col;   // rows 64..127
  const int vrow = 128 + ng * 16 + col;  // whi rows 128..191

  f32x4 accQ = {0,0,0,0}, accK = {0,0,0,0}, accV = {0,0,0,0};

  // 6 gl_lds per wave per step: 5 W-chunks (40 total) + 1 x-chunk (8 total).
#define STAGE(bp, s) do { \
    _Pragma("unroll") \
    for (int j = 0; j < 5; ++j) { \
      const int c_ = wv + 8 * j; \
      const short* src_; short* dst_; \
      if (c_ < 24) { \
        const int r_ = c_ * 8 + (lane >> 3); \
        const int lc_ = (lane & 7) ^ (r_ & 7); \
        src_ = wt_hi + (size_t)r_ * 1024 + (s) * 64 + lc_ * 8; \
        dst_ = (bp) + c_ * 512; \
      } else { \
        const int r_ = (c_ - 24) * 8 + (lane >> 3); \
        const int lc_ = (lane & 7) ^ (r_ & 7); \
        src_ = wt_lo + (size_t)r_ * 1024 + (s) * 64 + lc_ * 8; \
        dst_ = (bp) + 12288 + (c_ - 24) * 512; \
      } \
      gl_lds16(src_, dst_); \
    } \
    { \
      const int r_ = wv * 4 + (lane >> 4); \
      const int lc_ = (lane & 15) ^ (r_ & 15); \
      const float* xs_ = x + (size_t)(tokbase + r_) * 1024 + (s) * 64 + lc_ * 4; \
      float* xd_ = (float*)((bp) + 20480) + wv * 256; \
      gl_lds16(xs_, xd_); \
    } \
  } while (0)

#define PIPE_WAIT(N) do { \
    asm volatile("s_waitcnt vmcnt(" #N ")" ::: "memory"); \
    __builtin_amdgcn_s_barrier(); \
    __builtin_amdgcn_sched_barrier(0); \
  } while (0)
#define PIPE_END do { \
    asm volatile("s_waitcnt lgkmcnt(0)" ::: "memory"); \
    __builtin_amdgcn_sched_barrier(0); \
    __builtin_amdgcn_s_barrier(); \
  } while (0)

#define COMPUTE(bp) do { \
    const short* wb_ = (bp); \
    const float* xb_ = (const float*)((bp) + 20480); \
    _Pragma("unroll") \
    for (int h = 0; h < 2; ++h) { \
      const int hc_ = h * 8 + g * 2; \
      f32x4 x0_ = *(const f32x4*)(xb_ + arow * 64 + ((hc_       ^ (arow & 15)) << 2)); \
      f32x4 x1_ = *(const f32x4*)(xb_ + arow * 64 + (((hc_ + 1) ^ (arow & 15)) << 2)); \
      s16x8 xh_, xl_; \
      _Pragma("unroll") for (int i = 0; i < 4; ++i) { \
        short t0_ = f2bf(x0_[i]); xh_[i] = t0_; xl_[i] = f2bf(x0_[i] - bf2f(t0_)); \
        short t1_ = f2bf(x1_[i]); xh_[4 + i] = t1_; xl_[4 + i] = f2bf(x1_[i] - bf2f(t1_)); \
      } \
      const int wc_ = h * 4 + g; \
      s16x8 qh_ = *(const s16x8*)(wb_ + qrow * 64 + ((wc_ ^ (qrow & 7)) << 3)); \
      s16x8 kh_ = *(const s16x8*)(wb_ + krow * 64 + ((wc_ ^ (krow & 7)) << 3)); \
      s16x8 vh_ = *(const s16x8*)(wb_ + vrow * 64 + ((wc_ ^ (vrow & 7)) << 3)); \
      s16x8 ql_ = *(const s16x8*)(wb_ + 12288 + qrow * 64 + ((wc_ ^ (qrow & 7)) << 3)); \
      s16x8 kl_ = *(const s16x8*)(wb_ + 12288 + krow * 64 + ((wc_ ^ (krow & 7)) << 3)); \
      accQ = mfma32(xh_, qh_, accQ); \
      accK = mfma32(xh_, kh_, accK); \
      accV = mfma32(xh_, vh_, accV); \
      accQ = mfma32(xl_, qh_, accQ); \
      accK = mfma32(xl_, kh_, accK); \
      accQ = mfma32(xh_, ql_, accQ); \
      accK = mfma32(xh_, kl_, accK); \
    } \
  } while (0)

  short* b0 = &lds[0][0];
  short* b1 = &lds[1][0];
  short* b2 = &lds[2][0];

  // prologue: steps 0,1 in flight (12 outstanding/wave)
  STAGE(b0, 0);
  STAGE(b1, 1);
#pragma unroll 1
  for (int s = 0; s < 12; s += 3) {
    STAGE(b2, s + 2); PIPE_WAIT(12); COMPUTE(b0); PIPE_END;
    STAGE(b0, s + 3); PIPE_WAIT(12); COMPUTE(b1); PIPE_END;
    STAGE(b1, s + 4); PIPE_WAIT(12); COMPUTE(b2); PIPE_END;
  }
  STAGE(b2, 14); PIPE_WAIT(12); COMPUTE(b0); PIPE_END;   // step 12
  STAGE(b0, 15); PIPE_WAIT(12); COMPUTE(b1); PIPE_END;   // step 13
  PIPE_WAIT(6);  COMPUTE(b2); PIPE_END;                  // step 14
  PIPE_WAIT(0);  COMPUTE(b0); PIPE_END;                  // step 15

  // epilogue: bias, split, store. D: col(lane&15)=head idx, row(4g+r)=token.
  {
    const int hQ = ng * 16 + col;
    const float biasq = bq[hQ];
    const float biask = bk[hQ];
    const float biasv = bv[hQ];
#pragma unroll
    for (int r = 0; r < 4; ++r) {
      const int tok = tokbase + mg * 16 + 4 * g + r;
      float fq = accQ[r] + biasq;
      short qh = f2bf(fq);
      q_hi[(size_t)tok * 64 + hQ] = qh;
      q_lo[(size_t)tok * 64 + hQ] = f2bf(fq - bf2f(qh));
      float fk = accK[r] + biask;
      short kh = f2bf(fk);
      k_hi[(size_t)tok * 64 + hQ] = kh;
      k_lo[(size_t)tok * 64 + hQ] = f2bf(fk - bf2f(kh));
      const int bb = tok >> 11;
      const int tl = tok & 2047;
      v_t[((size_t)bb * 64 + hQ) * 2048 + tl] = f2bf(accV[r] + biasv);
    }
  }
#undef STAGE
#undef PIPE_WAIT
#undef PIPE_END
#undef COMPUTE
}

// ============================================================
// Kernel 2: causal flash attention. grid = 512 single-tile blocks (4b x 128t),
// LPT order (big t dispatched first), 512 thr, __launch_bounds__(512,4) ->
// VGPR<=128 -> 2 blocks/CU = 4 waves/SIMD (TLP hides KV L2 latency; no reg
// double-buffer needed). Waves split key-tiles mod 8; private online softmax;
// 8-way LDS merge. S^T = mfma(K,Q): D col=q, row=key == A-frag layout for PV.
// setprio(1) around MFMA clusters (waves desynced -> T5 applies).
// ============================================================
__global__ __launch_bounds__(512, 4) void attn(
    const short* __restrict__ q_hi, const short* __restrict__ q_lo,
    const short* __restrict__ k_hi, const short* __restrict__ k_lo,
    const short* __restrict__ v_t, float* __restrict__ out) {
  const int tid = threadIdx.x;
  const int lane = tid & 63;
  const int wv = tid >> 6;   // 0..7
  const int col = lane & 15;
  const int g = lane >> 4;
  const int bid = blockIdx.x;
  const int t = 127 - (bid >> 2);   // LPT: largest tiles first
  const int b = bid & 3;
  const int qb = t * 16;

  __shared__ float lds_O[8 * 64 * 18];   // 36 KiB
  __shared__ float lds_m[128];
  __shared__ float lds_l[128];

  const short* kh_b = k_hi + (size_t)b * 2048 * 64;
  const short* kl_b = k_lo + (size_t)b * 2048 * 64;
  const short* vt_b = v_t + (size_t)b * 64 * 2048;

  const short* qrh = q_hi + (size_t)(b * 2048 + qb + col) * 64 + g * 8;
  const short* qrl = q_lo + (size_t)(b * 2048 + qb + col) * 64 + g * 8;
  s16x8 qh0 = *(const s16x8*)(qrh);
  s16x8 qh1 = *(const s16x8*)(qrh + 32);
  s16x8 ql0 = *(const s16x8*)(qrl);
  s16x8 ql1 = *(const s16x8*)(qrl + 32);

  f32x4 o0 = {0,0,0,0}, o1 = {0,0,0,0}, o2 = {0,0,0,0}, o3 = {0,0,0,0};
  float m = -3.0e38f, l = 0.0f;

#pragma unroll 1
  for (int kt = wv; kt <= t; kt += 8) {
    const int kb = kt * 16;
    const short* krh = kh_b + (size_t)(kb + col) * 64 + g * 8;
    const short* krl = kl_b + (size_t)(kb + col) * 64 + g * 8;
    s16x8 kh0 = *(const s16x8*)(krh);
    s16x8 kh1 = *(const s16x8*)(krh + 32);
    s16x8 kl0 = *(const s16x8*)(krl);
    s16x8 kl1 = *(const s16x8*)(krl + 32);
    const short* vrow = vt_b + (size_t)col * 2048 + kb + 4 * g;
    s16x4 vf0 = *(const s16x4*)(vrow);
    s16x4 vf1 = *(const s16x4*)(vrow + 16 * 2048);
    s16x4 vf2 = *(const s16x4*)(vrow + 32 * 2048);
    s16x4 vf3 = *(const s16x4*)(vrow + 48 * 2048);

    // S^T: KhQh (chain A) + KhQl + KlQh (chain B)
    __builtin_amdgcn_s_setprio(1);
    f32x4 sA = {0,0,0,0}, sB = {0,0,0,0};
    sA = mfma32(kh0, qh0, sA); sA = mfma32(kh1, qh1, sA);
    sB = mfma32(kh0, ql0, sB); sB = mfma32(kh1, ql1, sB);
    sB = mfma32(kl0, qh0, sB); sB = mfma32(kl1, qh1, sB);
    __builtin_amdgcn_s_setprio(0);
    float s0 = sA[0] + sB[0];
    float s1 = sA[1] + sB[1];
    float s2 = sA[2] + sB[2];
    float s3 = sA[3] + sB[3];
    if (kt == t) {              // diagonal tile: key_local > q_local masked
      const int keyl = 4 * g;
      if (keyl + 0 > col) s0 = -3.0e38f;
      if (keyl + 1 > col) s1 = -3.0e38f;
      if (keyl + 2 > col) s2 = -3.0e38f;
      if (keyl + 3 > col) s3 = -3.0e38f;
    }
    float mx = fmaxf(fmaxf(s0, s1), fmaxf(s2, s3));
    mx = fmaxf(mx, __shfl_xor(mx, 16));
    mx = fmaxf(mx, __shfl_xor(mx, 32));
    const float mnew = fmaxf(m, mx);
    const float sc2 = __builtin_amdgcn_exp2f((m - mnew) * LOG2E);
    const float p0 = __builtin_amdgcn_exp2f((s0 - mnew) * LOG2E);
    const float p1 = __builtin_amdgcn_exp2f((s1 - mnew) * LOG2E);
    const float p2 = __builtin_amdgcn_exp2f((s2 - mnew) * LOG2E);
    const float p3 = __builtin_amdgcn_exp2f((s3 - mnew) * LOG2E);
    l = l * sc2 + (p0 + p1 + p2 + p3);   // group-partial l (reduced at merge)
    o0 *= sc2; o1 *= sc2; o2 *= sc2; o3 *= sc2;
    s16x4 pb;
    pb[0] = f2bf(p0); pb[1] = f2bf(p1); pb[2] = f2bf(p2); pb[3] = f2bf(p3);
    __builtin_amdgcn_s_setprio(1);
    o0 = mfma16(vf0, pb, o0);   // O^T[h][q], h = 4g+reg + 16*frag
    o1 = mfma16(vf1, pb, o1);
    o2 = mfma16(vf2, pb, o2);
    o3 = mfma16(vf3, pb, o3);
    __builtin_amdgcn_s_setprio(0);
    m = mnew;
  }

  // merge the 8 waves' partials through LDS (lean on registers)
  l += __shfl_xor(l, 16);
  l += __shfl_xor(l, 32);
  if (g == 0) {
    lds_m[wv * 16 + col] = m;
    lds_l[wv * 16 + col] = l;
  }
#pragma unroll
  for (int r = 0; r < 4; ++r) {
    lds_O[(wv * 64 +  0 + 4 * g + r) * 18 + col] = o0[r];
    lds_O[(wv * 64 + 16 + 4 * g + r) * 18 + col] = o1[r];
    lds_O[(wv * 64 + 32 + 4 * g + r) * 18 + col] = o2[r];
    lds_O[(wv * 64 + 48 + 4 * g + r) * 18 + col] = o3[r];
  }
  __syncthreads();
  {
    const int q = tid & 15;
    const int hh = tid >> 4;   // 0..31
    float M = lds_m[q];
#pragma unroll
    for (int w = 1; w < 8; ++w) M = fmaxf(M, lds_m[w * 16 + q]);
    float L = 0.0f;
#pragma unroll
    for (int w = 0; w < 8; ++w)
      L += __builtin_amdgcn_exp2f((lds_m[w * 16 + q] - M) * LOG2E) * lds_l[w * 16 + q];
    const float invL = 1.0f / L;
#pragma unroll
    for (int e = 0; e < 2; ++e) {
      const int h = hh * 2 + e;
      float acc = 0.0f;
#pragma unroll
      for (int w = 0; w < 8; ++w)
        acc += __builtin_amdgcn_exp2f((lds_m[w * 16 + q] - M) * LOG2E) *
               lds_O[(w * 64 + h) * 18 + q];
      out[(size_t)(b * 2048 + qb + q) * 64 + h] = acc * invL;
    }
  }
}

// ============================================================
extern "C" void kernel_launch(void* const* d_in, const int* in_sizes, int n_in,
                              void* d_out, int out_size, void* d_ws, size_t ws_size,
                              hipStream_t stream) {
  const float* x  = (const float*)d_in[0];
  const float* Wq = (const float*)d_in[1];
  const float* bq = (const float*)d_in[2];
  const float* Wk = (const float*)d_in[3];
  const float* bk = (const float*)d_in[4];
  const float* Wv = (const float*)d_in[5];
  const float* bv = (const float*)d_in[6];
  float* out = (float*)d_out;

  char* ws = (char*)d_ws;
  short* wt_hi = (short*)(ws);                       // 192*1024*2 = 393216 B
  short* wt_lo = (short*)(ws + 393216);
  short* q_hi  = (short*)(ws + 786432);              // 8192*64*2 = 1 MiB each
  short* q_lo  = (short*)(ws + 786432 + 1048576);
  short* k_hi  = (short*)(ws + 786432 + 2 * 1048576);
  short* k_lo  = (short*)(ws + 786432 + 3 * 1048576);
  short* v_t   = (short*)(ws + 786432 + 4 * 1048576);  // end: 6,029,312 B

  hipLaunchKernelGGL(prep_w, dim3(768), dim3(256), 0, stream, Wq, Wk, Wv, wt_hi, wt_lo);
  hipLaunchKernelGGL(proj_qkv, dim3(256), dim3(512), 0, stream,
                     x, wt_hi, wt_lo, bq, bk, bv, q_hi, q_lo, k_hi, k_lo, v_t);
  hipLaunchKernelGGL(attn, dim3(512), dim3(512), 0, stream,
                     q_hi, q_lo, k_hi, k_lo, v_t, out);
}

// Round 5
// 56.029 us; speedup vs baseline: 1.3516x; 1.3516x over previous
//
#include <hip/hip_runtime.h>

typedef float f32x4 __attribute__((ext_vector_type(4)));
typedef short s16x4 __attribute__((ext_vector_type(4)));
typedef short s16x8 __attribute__((ext_vector_type(8)));

#define LOG2E 1.4426950408889634f

// ---- bf16 helpers (bit-level, RNE) ----
__device__ __forceinline__ short f2bf(float f) {
  unsigned u = __float_as_uint(f);
  unsigned r = (u + 0x7fffu + ((u >> 16) & 1u)) >> 16;
  return (short)r;
}
__device__ __forceinline__ float bf2f(short s) {
  return __uint_as_float(((unsigned)(unsigned short)s) << 16);
}

// 16x16x16 bf16. D: col(lane&15)=B-idx, row(4g+reg)=A-idx  [HW-verified]
__device__ __forceinline__ f32x4 mfma16(s16x4 a, s16x4 b, f32x4 c) {
  return __builtin_amdgcn_mfma_f32_16x16x16bf16_1k(a, b, c, 0, 0, 0);
}
// 16x16x32 bf16 (gfx950). Same C/D layout. kappa-matched A/B (g,e)->g*8+e.
__device__ __forceinline__ f32x4 mfma32(s16x8 a, s16x8 b, f32x4 c) {
  return __builtin_amdgcn_mfma_f32_16x16x32_bf16(a, b, c, 0, 0, 0);
}

// async global->LDS, 16B/lane: HW writes lane i at (uniform dst)+i*16.
__device__ __forceinline__ void gl_lds16(const void* gp, void* sp) {
  __builtin_amdgcn_global_load_lds(
      (__attribute__((address_space(1))) void*)const_cast<void*>(gp),
      (__attribute__((address_space(3))) void*)sp, 16, 0, 0);
}

// ============================================================
// Kernel 0: split W^T into bf16 hi/lo.  wt[n][c], n: 0-63 q, 64-127 k, 128-191 v
// ============================================================
__global__ __launch_bounds__(256) void prep_w(
    const float* __restrict__ Wq, const float* __restrict__ Wk, const float* __restrict__ Wv,
    short* __restrict__ wt_hi, short* __restrict__ wt_lo) {
  int idx = blockIdx.x * 256 + threadIdx.x;   // 192*1024 total
  int n = idx >> 10;
  int c = idx & 1023;
  const float* W = (n < 64) ? Wq : ((n < 128) ? Wk : Wv);
  float v = W[c * 64 + (n & 63)];
  short hi = f2bf(v);
  short lo = f2bf(v - bf2f(hi));
  wt_hi[idx] = hi;
  wt_lo[idx] = lo;
}

// ============================================================
// Kernel 1: QKV projection — distance-2 gl_lds pipeline (UNCHANGED from R4).
// ============================================================
__global__ __launch_bounds__(512, 2) void proj_qkv(
    const float* __restrict__ x,
    const short* __restrict__ wt_hi, const short* __restrict__ wt_lo,
    const float* __restrict__ bq, const float* __restrict__ bk, const float* __restrict__ bv,
    short* __restrict__ q_hi, short* __restrict__ q_lo,
    short* __restrict__ k_hi, short* __restrict__ k_lo,
    short* __restrict__ v_t) {
  const int tid = threadIdx.x;
  const int lane = tid & 63;
  const int wv = tid >> 6;       // 0..7
  const int col = lane & 15;
  const int g = lane >> 4;       // 0..3
  const int mg = wv >> 2;        // 0..1
  const int ng = wv & 3;         // 0..3
  const int tokbase = blockIdx.x * 32;

  __shared__ short lds[3][24576];   // 3 x 48KB = 144KB

  const int arow = mg * 16 + col;        // x row 0..31
  const int qrow = ng * 16 + col;        // whi/wlo rows 0..63
  const int krow = 64 + ng * 16 + col;   // rows 64..127
  const int vrow = 128 + ng * 16 + col;  // whi rows 128..191

  f32x4 accQ = {0,0,0,0}, accK = {0,0,0,0}, accV = {0,0,0,0};

#define STAGE(bp, s) do { \
    _Pragma("unroll") \
    for (int j = 0; j < 5; ++j) { \
      const int c_ = wv + 8 * j; \
      const short* src_; short* dst_; \
      if (c_ < 24) { \
        const int r_ = c_ * 8 + (lane >> 3); \
        const int lc_ = (lane & 7) ^ (r_ & 7); \
        src_ = wt_hi + (size_t)r_ * 1024 + (s) * 64 + lc_ * 8; \
        dst_ = (bp) + c_ * 512; \
      } else { \
        const int r_ = (c_ - 24) * 8 + (lane >> 3); \
        const int lc_ = (lane & 7) ^ (r_ & 7); \
        src_ = wt_lo + (size_t)r_ * 1024 + (s) * 64 + lc_ * 8; \
        dst_ = (bp) + 12288 + (c_ - 24) * 512; \
      } \
      gl_lds16(src_, dst_); \
    } \
    { \
      const int r_ = wv * 4 + (lane >> 4); \
      const int lc_ = (lane & 15) ^ (r_ & 15); \
      const float* xs_ = x + (size_t)(tokbase + r_) * 1024 + (s) * 64 + lc_ * 4; \
      float* xd_ = (float*)((bp) + 20480) + wv * 256; \
      gl_lds16(xs_, xd_); \
    } \
  } while (0)

#define PIPE_WAIT(N) do { \
    asm volatile("s_waitcnt vmcnt(" #N ")" ::: "memory"); \
    __builtin_amdgcn_s_barrier(); \
    __builtin_amdgcn_sched_barrier(0); \
  } while (0)
#define PIPE_END do { \
    asm volatile("s_waitcnt lgkmcnt(0)" ::: "memory"); \
    __builtin_amdgcn_sched_barrier(0); \
    __builtin_amdgcn_s_barrier(); \
  } while (0)

#define COMPUTE(bp) do { \
    const short* wb_ = (bp); \
    const float* xb_ = (const float*)((bp) + 20480); \
    _Pragma("unroll") \
    for (int h = 0; h < 2; ++h) { \
      const int hc_ = h * 8 + g * 2; \
      f32x4 x0_ = *(const f32x4*)(xb_ + arow * 64 + ((hc_       ^ (arow & 15)) << 2)); \
      f32x4 x1_ = *(const f32x4*)(xb_ + arow * 64 + (((hc_ + 1) ^ (arow & 15)) << 2)); \
      s16x8 xh_, xl_; \
      _Pragma("unroll") for (int i = 0; i < 4; ++i) { \
        short t0_ = f2bf(x0_[i]); xh_[i] = t0_; xl_[i] = f2bf(x0_[i] - bf2f(t0_)); \
        short t1_ = f2bf(x1_[i]); xh_[4 + i] = t1_; xl_[4 + i] = f2bf(x1_[i] - bf2f(t1_)); \
      } \
      const int wc_ = h * 4 + g; \
      s16x8 qh_ = *(const s16x8*)(wb_ + qrow * 64 + ((wc_ ^ (qrow & 7)) << 3)); \
      s16x8 kh_ = *(const s16x8*)(wb_ + krow * 64 + ((wc_ ^ (krow & 7)) << 3)); \
      s16x8 vh_ = *(const s16x8*)(wb_ + vrow * 64 + ((wc_ ^ (vrow & 7)) << 3)); \
      s16x8 ql_ = *(const s16x8*)(wb_ + 12288 + qrow * 64 + ((wc_ ^ (qrow & 7)) << 3)); \
      s16x8 kl_ = *(const s16x8*)(wb_ + 12288 + krow * 64 + ((wc_ ^ (krow & 7)) << 3)); \
      accQ = mfma32(xh_, qh_, accQ); \
      accK = mfma32(xh_, kh_, accK); \
      accV = mfma32(xh_, vh_, accV); \
      accQ = mfma32(xl_, qh_, accQ); \
      accK = mfma32(xl_, kh_, accK); \
      accQ = mfma32(xh_, ql_, accQ); \
      accK = mfma32(xh_, kl_, accK); \
    } \
  } while (0)

  short* b0 = &lds[0][0];
  short* b1 = &lds[1][0];
  short* b2 = &lds[2][0];

  STAGE(b0, 0);
  STAGE(b1, 1);
#pragma unroll 1
  for (int s = 0; s < 12; s += 3) {
    STAGE(b2, s + 2); PIPE_WAIT(6); COMPUTE(b0); PIPE_END;
    STAGE(b0, s + 3); PIPE_WAIT(6); COMPUTE(b1); PIPE_END;
    STAGE(b1, s + 4); PIPE_WAIT(6); COMPUTE(b2); PIPE_END;
  }
  STAGE(b2, 14); PIPE_WAIT(6); COMPUTE(b0); PIPE_END;   // step 12
  STAGE(b0, 15); PIPE_WAIT(6); COMPUTE(b1); PIPE_END;   // step 13
  PIPE_WAIT(3);  COMPUTE(b2); PIPE_END;                  // step 14
  PIPE_WAIT(0);  COMPUTE(b0); PIPE_END;                  // step 15

  {
    const int hQ = ng * 16 + col;
    const float biasq = bq[hQ];
    const float biask = bk[hQ];
    const float biasv = bv[hQ];
#pragma unroll
    for (int r = 0; r < 4; ++r) {
      const int tok = tokbase + mg * 16 + 4 * g + r;
      float fq = accQ[r] + biasq;
      short qh = f2bf(fq);
      q_hi[(size_t)tok * 64 + hQ] = qh;
      q_lo[(size_t)tok * 64 + hQ] = f2bf(fq - bf2f(qh));
      float fk = accK[r] + biask;
      short kh = f2bf(fk);
      k_hi[(size_t)tok * 64 + hQ] = kh;
      k_lo[(size_t)tok * 64 + hQ] = f2bf(fk - bf2f(kh));
      const int bb = tok >> 11;
      const int tl = tok & 2047;
      v_t[((size_t)bb * 64 + hQ) * 2048 + tl] = f2bf(accV[r] + biasv);
    }
  }
#undef STAGE
#undef COMPUTE
}

// ============================================================
// Kernel 2: causal flash attention, split-K + LDS-staged K/V.
// grid 256 = (s:8, b:4, p:8). Block: 8 waves x 32 q-rows = rows [256p,256p+256)
// of batch b; keys [256s, 256s+256) in 4 steps of KVBLK=64. s>p -> exit.
// Staging: gl_lds triple-buffer (3x24KB), counted vmcnt(6/3/0) (proj pattern).
// LDS buffer (shorts): khi[64][64]@0 (row-XOR chunk swizzle, src-preswizzled),
// klo@4096, v^T[64h][64k]@8192. Per wave: 2 q-tiles (A=rows qlo..+15,
// B=+16..+31) share every K/V fragment. One softmax update per 64 keys.
// Partials (m,l,O^T) per q-row per split -> pm/pl/pO; reduce_p combines.
// ============================================================
__global__ __launch_bounds__(512, 2) void attn(
    const short* __restrict__ q_hi, const short* __restrict__ q_lo,
    const short* __restrict__ k_hi, const short* __restrict__ k_lo,
    const short* __restrict__ v_t,
    float* __restrict__ pm, float* __restrict__ pl, float* __restrict__ pO) {
  const int tid = threadIdx.x;
  const int lane = tid & 63;
  const int w = tid >> 6;        // wave 0..7
  const int col = lane & 15;
  const int g = lane >> 4;
  const int bid = blockIdx.x;
  const int p = bid & 7;
  const int b = (bid >> 3) & 3;
  const int s = bid >> 5;
  if (s > p) return;             // fully above diagonal: no work (uniform exit)

  __shared__ short lds[3][12288];   // 3 x 24KB

  const int qlo = 256 * p + 32 * w;   // batch-local base q row of this wave
  const int kb0 = 256 * s;            // batch-local first key of this split

  // ---- Q fragments (once), then drain vmcnt so counted waits are exact ----
  const short* qbh = q_hi + (size_t)(b * 2048 + qlo + col) * 64 + g * 8;
  const short* qbl = q_lo + (size_t)(b * 2048 + qlo + col) * 64 + g * 8;
  s16x8 qh0a = *(const s16x8*)(qbh);
  s16x8 qh1a = *(const s16x8*)(qbh + 32);
  s16x8 ql0a = *(const s16x8*)(qbl);
  s16x8 ql1a = *(const s16x8*)(qbl + 32);
  s16x8 qh0b = *(const s16x8*)(qbh + 16 * 64);
  s16x8 qh1b = *(const s16x8*)(qbh + 16 * 64 + 32);
  s16x8 ql0b = *(const s16x8*)(qbl + 16 * 64);
  s16x8 ql1b = *(const s16x8*)(qbl + 16 * 64 + 32);
  asm volatile("s_waitcnt vmcnt(0)" ::: "memory");
  __builtin_amdgcn_sched_barrier(0);

  f32x4 oA0 = {0,0,0,0}, oA1 = {0,0,0,0}, oA2 = {0,0,0,0}, oA3 = {0,0,0,0};
  f32x4 oB0 = {0,0,0,0}, oB1 = {0,0,0,0}, oB2 = {0,0,0,0}, oB3 = {0,0,0,0};
  float mA = -3.0e38f, lA = 0.0f, mB = -3.0e38f, lB = 0.0f;
  const f32x4 NEGV = {-3.0e38f, -3.0e38f, -3.0e38f, -3.0e38f};

  // 3 gl_lds per wave per step (Khi 1KB, Klo 1KB, V 1KB); rows 8w..8w+7.
#define STAGE(BP, J) do { \
    const int kbs_ = kb0 + 64 * (J); \
    const int r_ = 8 * w + (lane >> 3); \
    const int lc_ = (lane & 7) ^ (lane >> 3); \
    gl_lds16(k_hi + (size_t)(b * 2048 + kbs_ + r_) * 64 + lc_ * 8, (BP) + 8 * w * 64); \
    gl_lds16(k_lo + (size_t)(b * 2048 + kbs_ + r_) * 64 + lc_ * 8, (BP) + 4096 + 8 * w * 64); \
    gl_lds16(v_t + ((size_t)b * 64 + r_) * 2048 + kbs_ + lc_ * 8, (BP) + 8192 + 8 * w * 64); \
  } while (0)

#define PIPE_WAIT(N) do { \
    asm volatile("s_waitcnt vmcnt(" #N ")" ::: "memory"); \
    __builtin_amdgcn_s_barrier(); \
    __builtin_amdgcn_sched_barrier(0); \
  } while (0)
#define PIPE_END do { \
    asm volatile("s_waitcnt lgkmcnt(0)" ::: "memory"); \
    __builtin_amdgcn_sched_barrier(0); \
    __builtin_amdgcn_s_barrier(); \
  } while (0)

  // QK for subtile U (keys kb_+16U..+15): read K frags once, feed both q-tiles.
#define QK_U(U) do { \
    const int kg0_ = kb_ + 16 * U; \
    if (kg0_ <= qlo + 31) { \
      const short* kr_ = bp_ + (16 * U + col) * 64; \
      const int cx_ = col & 7; \
      s16x8 kh0_ = *(const s16x8*)(kr_ + ((g ^ cx_) << 3)); \
      s16x8 kh1_ = *(const s16x8*)(kr_ + (((4 + g) ^ cx_) << 3)); \
      s16x8 kl0_ = *(const s16x8*)(kr_ + 4096 + ((g ^ cx_) << 3)); \
      s16x8 kl1_ = *(const s16x8*)(kr_ + 4096 + (((4 + g) ^ cx_) << 3)); \
      if (kg0_ <= qlo + 15) { \
        f32x4 u1_ = {0,0,0,0}, u2_ = {0,0,0,0}; \
        u1_ = mfma32(kh0_, qh0a, u1_); u1_ = mfma32(kh1_, qh1a, u1_); \
        u2_ = mfma32(kh0_, ql0a, u2_); u2_ = mfma32(kh1_, ql1a, u2_); \
        u2_ = mfma32(kl0_, qh0a, u2_); u2_ = mfma32(kl1_, qh1a, u2_); \
        scA##U = u1_ + u2_; \
        if (kg0_ == qlo) { \
          _Pragma("unroll") for (int i = 0; i < 4; ++i) \
            if (4 * g + i > col) scA##U[i] = -3.0e38f; \
        } \
      } \
      { \
        f32x4 u1_ = {0,0,0,0}, u2_ = {0,0,0,0}; \
        u1_ = mfma32(kh0_, qh0b, u1_); u1_ = mfma32(kh1_, qh1b, u1_); \
        u2_ = mfma32(kh0_, ql0b, u2_); u2_ = mfma32(kh1_, ql1b, u2_); \
        u2_ = mfma32(kl0_, qh0b, u2_); u2_ = mfma32(kl1_, qh1b, u2_); \
        scB##U = u1_ + u2_; \
        if (kg0_ == qlo + 16) { \
          _Pragma("unroll") for (int i = 0; i < 4; ++i) \
            if (4 * g + i > col) scB##U[i] = -3.0e38f; \
        } \
      } \
    } \
  } while (0)

#define SMAX4(v) fmaxf(fmaxf((v)[0], (v)[1]), fmaxf((v)[2], (v)[3]))

#define SOFTMAX_X(s0v, s1v, s2v, s3v, mX, lX, o0X, o1X, o2X, o3X, p0X, p1X, p2X, p3X) do { \
    float mx_ = fmaxf(fmaxf(SMAX4(s0v), SMAX4(s1v)), fmaxf(SMAX4(s2v), SMAX4(s3v))); \
    mx_ = fmaxf(mx_, __shfl_xor(mx_, 16)); \
    mx_ = fmaxf(mx_, __shfl_xor(mx_, 32)); \
    const float mn_ = fmaxf(mX, mx_); \
    const float rs_ = __builtin_amdgcn_exp2f((mX - mn_) * LOG2E); \
    float ls_ = 0.f; \
    _Pragma("unroll") for (int i = 0; i < 4; ++i) { \
      float e0_ = __builtin_amdgcn_exp2f((s0v[i] - mn_) * LOG2E); \
      float e1_ = __builtin_amdgcn_exp2f((s1v[i] - mn_) * LOG2E); \
      float e2_ = __builtin_amdgcn_exp2f((s2v[i] - mn_) * LOG2E); \
      float e3_ = __builtin_amdgcn_exp2f((s3v[i] - mn_) * LOG2E); \
      p0X[i] = f2bf(e0_); p1X[i] = f2bf(e1_); p2X[i] = f2bf(e2_); p3X[i] = f2bf(e3_); \
      ls_ += e0_ + e1_ + e2_ + e3_; \
    } \
    lX = lX * rs_ + ls_; \
    o0X *= rs_; o1X *= rs_; o2X *= rs_; o3X *= rs_; \
    mX = mn_; \
  } while (0)

  // PV for subtile U: V^T frags shared by both q-tiles.
#define PV_U(U) do { \
    const int kg0_ = kb_ + 16 * U; \
    if (kg0_ <= qlo + 31) { \
      const int cx_ = col & 7; \
      const short* vr_ = bp_ + 8192 + col * 64 + ((g & 1) << 2) + \
                         (((2 * U + (g >> 1)) ^ cx_) << 3); \
      s16x4 v0_ = *(const s16x4*)(vr_); \
      s16x4 v1_ = *(const s16x4*)(vr_ + 1024); \
      s16x4 v2_ = *(const s16x4*)(vr_ + 2048); \
      s16x4 v3_ = *(const s16x4*)(vr_ + 3072); \
      if (kg0_ <= qlo + 15) { \
        oA0 = mfma16(v0_, pbA##U, oA0); \
        oA1 = mfma16(v1_, pbA##U, oA1); \
        oA2 = mfma16(v2_, pbA##U, oA2); \
        oA3 = mfma16(v3_, pbA##U, oA3); \
      } \
      oB0 = mfma16(v0_, pbB##U, oB0); \
      oB1 = mfma16(v1_, pbB##U, oB1); \
      oB2 = mfma16(v2_, pbB##U, oB2); \
      oB3 = mfma16(v3_, pbB##U, oB3); \
    } \
  } while (0)

#define COMPUTE(BP, J) do { \
    const int kb_ = kb0 + 64 * (J); \
    if (kb_ <= qlo + 31) { \
      const short* bp_ = (BP); \
      f32x4 scA0 = NEGV, scA1 = NEGV, scA2 = NEGV, scA3 = NEGV; \
      f32x4 scB0 = NEGV, scB1 = NEGV, scB2 = NEGV, scB3 = NEGV; \
      QK_U(0); QK_U(1); QK_U(2); QK_U(3); \
      s16x4 pbA0, pbA1, pbA2, pbA3, pbB0, pbB1, pbB2, pbB3; \
      if (kb_ <= qlo + 15) \
        SOFTMAX_X(scA0, scA1, scA2, scA3, mA, lA, oA0, oA1, oA2, oA3, \
                  pbA0, pbA1, pbA2, pbA3); \
      SOFTMAX_X(scB0, scB1, scB2, scB3, mB, lB, oB0, oB1, oB2, oB3, \
                pbB0, pbB1, pbB2, pbB3); \
      PV_U(0); PV_U(1); PV_U(2); PV_U(3); \
    } \
  } while (0)

  short* L0 = &lds[0][0];
  short* L1 = &lds[1][0];
  short* L2 = &lds[2][0];

  STAGE(L0, 0); STAGE(L1, 1);
  STAGE(L2, 2); PIPE_WAIT(6); COMPUTE(L0, 0); PIPE_END;
  STAGE(L0, 3); PIPE_WAIT(6); COMPUTE(L1, 1); PIPE_END;
  PIPE_WAIT(3); COMPUTE(L2, 2); PIPE_END;
  PIPE_WAIT(0); COMPUTE(L0, 3);

  // ---- store per-split partials (every wave of an active block has work) ----
  lA += __shfl_xor(lA, 16); lA += __shfl_xor(lA, 32);
  lB += __shfl_xor(lB, 16); lB += __shfl_xor(lB, 32);
  const int rowA = b * 2048 + qlo + col;
  const int rowB = rowA + 16;
  if (g == 0) {
    pm[s * 8192 + rowA] = mA;  pl[s * 8192 + rowA] = lA;
    pm[s * 8192 + rowB] = mB;  pl[s * 8192 + rowB] = lB;
  }
  {
    float* dA = pO + ((size_t)s * 8192 + rowA) * 64 + 4 * g;
    float* dB = pO + ((size_t)s * 8192 + rowB) * 64 + 4 * g;
    *(f32x4*)(dA)      = oA0; *(f32x4*)(dA + 16) = oA1;
    *(f32x4*)(dA + 32) = oA2; *(f32x4*)(dA + 48) = oA3;
    *(f32x4*)(dB)      = oB0; *(f32x4*)(dB + 16) = oB1;
    *(f32x4*)(dB + 32) = oB2; *(f32x4*)(dB + 48) = oB3;
  }
#undef STAGE
#undef PIPE_WAIT
#undef PIPE_END
#undef QK_U
#undef SMAX4
#undef SOFTMAX_X
#undef PV_U
#undef COMPUTE
}

// ============================================================
// Kernel 3: combine split-K partials. out[row][h] = sum_s w_s*O_s / sum_s w_s*l_s
// grid 512 x 256: thread -> (row, 4h). Row r needs splits s = 0..(r&2047)>>8.
// ============================================================
__global__ __launch_bounds__(256) void reduce_p(
    const float* __restrict__ pm, const float* __restrict__ pl,
    const float* __restrict__ pO, float* __restrict__ out) {
  const int idx = blockIdx.x * 256 + threadIdx.x;   // 131072
  const int row = idx >> 4;
  const int hq = (idx & 15) * 4;
  const int smax = (row & 2047) >> 8;
  float M = -3.0e38f;
  for (int s = 0; s <= smax; ++s) M = fmaxf(M, pm[s * 8192 + row]);
  float L = 0.f;
  f32x4 acc = {0, 0, 0, 0};
  for (int s = 0; s <= smax; ++s) {
    const float ws = __builtin_amdgcn_exp2f((pm[s * 8192 + row] - M) * LOG2E);
    L += ws * pl[s * 8192 + row];
    f32x4 ov = *(const f32x4*)(pO + ((size_t)s * 8192 + row) * 64 + hq);
    acc += ov * ws;
  }
  const float invL = 1.0f / L;
  *(f32x4*)(out + (size_t)row * 64 + hq) = acc * invL;
}

// ============================================================
extern "C" void kernel_launch(void* const* d_in, const int* in_sizes, int n_in,
                              void* d_out, int out_size, void* d_ws, size_t ws_size,
                              hipStream_t stream) {
  const float* x  = (const float*)d_in[0];
  const float* Wq = (const float*)d_in[1];
  const float* bq = (const float*)d_in[2];
  const float* Wk = (const float*)d_in[3];
  const float* bk = (const float*)d_in[4];
  const float* Wv = (const float*)d_in[5];
  const float* bv = (const float*)d_in[6];
  float* out = (float*)d_out;

  char* ws = (char*)d_ws;
  short* wt_hi = (short*)(ws);                       // 192*1024*2 = 393216 B
  short* wt_lo = (short*)(ws + 393216);
  short* q_hi  = (short*)(ws + 786432);              // 8192*64*2 = 1 MiB each
  short* q_lo  = (short*)(ws + 786432 + 1048576);
  short* k_hi  = (short*)(ws + 786432 + 2 * 1048576);
  short* k_lo  = (short*)(ws + 786432 + 3 * 1048576);
  short* v_t   = (short*)(ws + 786432 + 4 * 1048576);  // end: 6,029,312 B
  float* pm    = (float*)(ws + 6029312);               // 8*8192*4 = 262144 B
  float* pl    = (float*)(ws + 6291456);               // 262144 B
  float* pO    = (float*)(ws + 6553600);               // 8*8192*64*4 = 16 MiB

  hipLaunchKernelGGL(prep_w, dim3(768), dim3(256), 0, stream, Wq, Wk, Wv, wt_hi, wt_lo);
  hipLaunchKernelGGL(proj_qkv, dim3(256), dim3(512), 0, stream,
                     x, wt_hi, wt_lo, bq, bk, bv, q_hi, q_lo, k_hi, k_lo, v_t);
  hipLaunchKernelGGL(attn, dim3(256), dim3(512), 0, stream,
                     q_hi, q_lo, k_hi, k_lo, v_t, pm, pl, pO);
  hipLaunchKernelGGL(reduce_p, dim3(512), dim3(256), 0, stream, pm, pl, pO, out);
}

// Round 6
// 55.422 us; speedup vs baseline: 1.3665x; 1.0110x over previous
//
#include <hip/hip_runtime.h>

typedef float f32x4 __attribute__((ext_vector_type(4)));
typedef short s16x4 __attribute__((ext_vector_type(4)));
typedef short s16x8 __attribute__((ext_vector_type(8)));

#define LOG2E 1.4426950408889634f

// ---- bf16 helpers (bit-level, RNE) ----
__device__ __forceinline__ short f2bf(float f) {
  unsigned u = __float_as_uint(f);
  unsigned r = (u + 0x7fffu + ((u >> 16) & 1u)) >> 16;
  return (short)r;
}
__device__ __forceinline__ float bf2f(short s) {
  return __uint_as_float(((unsigned)(unsigned short)s) << 16);
}
// packed f32->bf16 (RNE), 2 elems/inst. D[15:0]=cvt(a), D[31:16]=cvt(b).
__device__ __forceinline__ unsigned cvt_pk_bf16(float a, float b) {
  unsigned r;
  asm("v_cvt_pk_bf16_f32 %0, %1, %2" : "=v"(r) : "v"(a), "v"(b));
  return r;
}

// 16x16x16 bf16. D: col(lane&15)=B-idx, row(4g+reg)=A-idx  [HW-verified]
__device__ __forceinline__ f32x4 mfma16(s16x4 a, s16x4 b, f32x4 c) {
  return __builtin_amdgcn_mfma_f32_16x16x16bf16_1k(a, b, c, 0, 0, 0);
}
// 16x16x32 bf16 (gfx950). Same C/D layout. kappa-matched A/B (g,e)->g*8+e.
__device__ __forceinline__ f32x4 mfma32(s16x8 a, s16x8 b, f32x4 c) {
  return __builtin_amdgcn_mfma_f32_16x16x32_bf16(a, b, c, 0, 0, 0);
}

// async global->LDS, 16B/lane: HW writes lane i at (uniform dst)+i*16.
__device__ __forceinline__ void gl_lds16(const void* gp, void* sp) {
  __builtin_amdgcn_global_load_lds(
      (__attribute__((address_space(1))) void*)const_cast<void*>(gp),
      (__attribute__((address_space(3))) void*)sp, 16, 0, 0);
}

// ============================================================
// Kernel 0: split W^T into bf16 hi/lo.  wt[n][c], n: 0-63 q, 64-127 k, 128-191 v
// ============================================================
__global__ __launch_bounds__(256) void prep_w(
    const float* __restrict__ Wq, const float* __restrict__ Wk, const float* __restrict__ Wv,
    short* __restrict__ wt_hi, short* __restrict__ wt_lo) {
  int idx = blockIdx.x * 256 + threadIdx.x;   // 192*1024 total
  int n = idx >> 10;
  int c = idx & 1023;
  const float* W = (n < 64) ? Wq : ((n < 128) ? Wk : Wv);
  float v = W[c * 64 + (n & 63)];
  short hi = f2bf(v);
  short lo = f2bf(v - bf2f(hi));
  wt_hi[idx] = hi;
  wt_lo[idx] = lo;
}

// ============================================================
// Kernel 1: QKV projection — BK=32, 5-buffer distance-4 gl_lds pipeline.
// grid 256 x 512 thr (8 waves = mg:2 x ng:4). BM=32 tokens, 32 K-steps.
// Per step: 24 x 1KB chunks (whi 12 + wlo 8 + x-f32 4) = 3 gl_lds/wave
// -> uniform per-wave vmcnt: steady 12 (distance-4), tail 9/6/3/0.
// Buffer (shorts): whi[192][32]@0, wlo[128][32]@6144, xf32[32][32]@10240. 24KB.
// Swizzles (src-preswizzled, linear DMA dest, same involution on read):
//   W 16B-slot: phys = g ^ ((row>>1)&3)  (row stride 64B -> 2-way, free)
//   x 16B-quad: phys = q ^ (row&7)       (row stride 128B -> 2-way, free)
// x split to bf16 hi/lo in-consumer via v_cvt_pk_bf16_f32 (residual exact).
// ============================================================
__global__ __launch_bounds__(512, 2) void proj_qkv(
    const float* __restrict__ x,
    const short* __restrict__ wt_hi, const short* __restrict__ wt_lo,
    const float* __restrict__ bq, const float* __restrict__ bk, const float* __restrict__ bv,
    short* __restrict__ q_hi, short* __restrict__ q_lo,
    short* __restrict__ k_hi, short* __restrict__ k_lo,
    short* __restrict__ v_t) {
  const int tid = threadIdx.x;
  const int lane = tid & 63;
  const int wv = tid >> 6;       // 0..7
  const int col = lane & 15;
  const int g = lane >> 4;       // 0..3
  const int mg = wv >> 2;        // 0..1
  const int ng = wv & 3;         // 0..3
  const int tokbase = blockIdx.x * 32;

  __shared__ short lds[5][12288];   // 5 x 24KB = 120KB

  // ---- staging: wave owns chunks {wv, wv+8, wv+16} ----
  const int wsl = ((lane & 3) ^ ((lane >> 3) & 3)) * 8;   // W src slot (shorts)
  // chunk0 = wv (0..7): always whi, rows 16*wv..
  const short* s0 = wt_hi + (size_t)(16 * wv + (lane >> 2)) * 1024 + wsl;
  const int d0 = wv * 512;
  // chunk1 = wv+8 (8..15): whi rows 128.. (c<12) or wlo rows 0.. (c>=12)
  const int c1 = wv + 8;
  const short* s1 = (c1 < 12 ? wt_hi + (size_t)(16 * c1 + (lane >> 2)) * 1024
                             : wt_lo + (size_t)(16 * (c1 - 12) + (lane >> 2)) * 1024) + wsl;
  const int d1 = (c1 < 12) ? c1 * 512 : 6144 + (c1 - 12) * 512;
  // chunk2 = wv+16 (16..19 wlo rows 64..127 ; 20..23 x rows 8*(c2-20)..)
  const int c2 = wv + 16;
  const bool isx = (c2 >= 20);
  const short* s2 = isx
      ? (const short*)(x + (size_t)(tokbase + 8 * (c2 - 20) + (lane >> 3)) * 1024 +
                       ((lane & 7) ^ (lane >> 3)) * 4)
      : wt_lo + (size_t)(16 * (c2 - 12) + (lane >> 2)) * 1024 + wsl;
  const int d2 = isx ? 10240 + (c2 - 20) * 512 : 6144 + (c2 - 12) * 512;
  const int st2 = isx ? 64 : 32;   // per-step src advance in shorts

#define STAGE(BP, S) do { \
    gl_lds16(s0 + (S) * 32, (BP) + d0); \
    gl_lds16(s1 + (S) * 32, (BP) + d1); \
    gl_lds16(s2 + (S) * st2, (BP) + d2); \
  } while (0)

#define PIPE_WAIT(N) do { \
    asm volatile("s_waitcnt vmcnt(" #N ")" ::: "memory"); \
    __builtin_amdgcn_s_barrier(); \
    __builtin_amdgcn_sched_barrier(0); \
  } while (0)
#define PIPE_END do { \
    asm volatile("s_waitcnt lgkmcnt(0)" ::: "memory"); \
    __builtin_amdgcn_sched_barrier(0); \
    __builtin_amdgcn_s_barrier(); \
  } while (0)

  // ---- compute-side (step-invariant offsets) ----
  const int arow = mg * 16 + col;                 // x row
  const int xq0 = ((2 * g) ^ (arow & 7)) << 2;    // f32 offsets within x row
  const int xq1 = ((2 * g + 1) ^ (arow & 7)) << 2;
  const int rq = ng * 16 + col;                   // W row (q); k:+64, v:+128
  const int ws = (g ^ ((rq >> 1) & 3)) << 3;      // W slot (shorts)

  f32x4 accQ = {0,0,0,0}, accK = {0,0,0,0}, accV = {0,0,0,0};

  typedef union { unsigned u[4]; s16x8 v8; } pk8;

#define COMPUTE(BP) do { \
    const short* bp_ = (BP); \
    const float* xb_ = (const float*)(bp_ + 10240); \
    f32x4 x0_ = *(const f32x4*)(xb_ + arow * 32 + xq0); \
    f32x4 x1_ = *(const f32x4*)(xb_ + arow * 32 + xq1); \
    pk8 xh_, xl_; \
    xh_.u[0] = cvt_pk_bf16(x0_[0], x0_[1]); \
    xh_.u[1] = cvt_pk_bf16(x0_[2], x0_[3]); \
    xh_.u[2] = cvt_pk_bf16(x1_[0], x1_[1]); \
    xh_.u[3] = cvt_pk_bf16(x1_[2], x1_[3]); \
    xl_.u[0] = cvt_pk_bf16(x0_[0] - __uint_as_float(xh_.u[0] << 16), \
                           x0_[1] - __uint_as_float(xh_.u[0] & 0xffff0000u)); \
    xl_.u[1] = cvt_pk_bf16(x0_[2] - __uint_as_float(xh_.u[1] << 16), \
                           x0_[3] - __uint_as_float(xh_.u[1] & 0xffff0000u)); \
    xl_.u[2] = cvt_pk_bf16(x1_[0] - __uint_as_float(xh_.u[2] << 16), \
                           x1_[1] - __uint_as_float(xh_.u[2] & 0xffff0000u)); \
    xl_.u[3] = cvt_pk_bf16(x1_[2] - __uint_as_float(xh_.u[3] << 16), \
                           x1_[3] - __uint_as_float(xh_.u[3] & 0xffff0000u)); \
    s16x8 qh_ = *(const s16x8*)(bp_ + rq * 32 + ws); \
    s16x8 kh_ = *(const s16x8*)(bp_ + (64 + rq) * 32 + ws); \
    s16x8 vh_ = *(const s16x8*)(bp_ + (128 + rq) * 32 + ws); \
    s16x8 ql_ = *(const s16x8*)(bp_ + 6144 + rq * 32 + ws); \
    s16x8 kl_ = *(const s16x8*)(bp_ + 6144 + (64 + rq) * 32 + ws); \
    accQ = mfma32(xh_.v8, qh_, accQ); \
    accK = mfma32(xh_.v8, kh_, accK); \
    accV = mfma32(xh_.v8, vh_, accV); \
    accQ = mfma32(xl_.v8, qh_, accQ); \
    accK = mfma32(xl_.v8, kh_, accK); \
    accQ = mfma32(xh_.v8, ql_, accQ); \
    accK = mfma32(xh_.v8, kl_, accK); \
  } while (0)

  short* cA = &lds[0][0];
  short* cB = &lds[1][0];
  short* cC = &lds[2][0];
  short* cD = &lds[3][0];
  short* cE = &lds[4][0];

  // prologue: steps 0..3 in flight (12 outstanding/wave)
  STAGE(cA, 0); STAGE(cB, 1); STAGE(cC, 2); STAGE(cD, 3);

#pragma unroll 1
  for (int b = 0; b < 28; ++b) {
    STAGE(cE, b + 4);
    PIPE_WAIT(12);          // drains step b's group (distance-4)
    COMPUTE(cA);
    PIPE_END;
    short* t = cA; cA = cB; cB = cC; cC = cD; cD = cE; cE = t;
  }
  PIPE_WAIT(9); COMPUTE(cA); PIPE_END;   // b=28
  PIPE_WAIT(6); COMPUTE(cB); PIPE_END;   // b=29
  PIPE_WAIT(3); COMPUTE(cC); PIPE_END;   // b=30
  PIPE_WAIT(0); COMPUTE(cD);             // b=31

  // epilogue: bias, split, store. D: col(lane&15)=head idx, row(4g+r)=token.
  {
    const int hQ = ng * 16 + col;
    const float biasq = bq[hQ];
    const float biask = bk[hQ];
    const float biasv = bv[hQ];
#pragma unroll
    for (int r = 0; r < 4; ++r) {
      const int tok = tokbase + mg * 16 + 4 * g + r;
      float fq = accQ[r] + biasq;
      short qh = f2bf(fq);
      q_hi[(size_t)tok * 64 + hQ] = qh;
      q_lo[(size_t)tok * 64 + hQ] = f2bf(fq - bf2f(qh));
      float fk = accK[r] + biask;
      short kh = f2bf(fk);
      k_hi[(size_t)tok * 64 + hQ] = kh;
      k_lo[(size_t)tok * 64 + hQ] = f2bf(fk - bf2f(kh));
      const int bb = tok >> 11;
      const int tl = tok & 2047;
      v_t[((size_t)bb * 64 + hQ) * 2048 + tl] = f2bf(accV[r] + biasv);
    }
  }
#undef STAGE
#undef PIPE_WAIT
#undef PIPE_END
#undef COMPUTE
}

// ============================================================
// Kernel 2: causal flash attention, split-K + LDS-staged K/V (UNCHANGED R5).
// ============================================================
__global__ __launch_bounds__(512, 2) void attn(
    const short* __restrict__ q_hi, const short* __restrict__ q_lo,
    const short* __restrict__ k_hi, const short* __restrict__ k_lo,
    const short* __restrict__ v_t,
    float* __restrict__ pm, float* __restrict__ pl, float* __restrict__ pO) {
  const int tid = threadIdx.x;
  const int lane = tid & 63;
  const int w = tid >> 6;        // wave 0..7
  const int col = lane & 15;
  const int g = lane >> 4;
  const int bid = blockIdx.x;
  const int p = bid & 7;
  const int b = (bid >> 3) & 3;
  const int s = bid >> 5;
  if (s > p) return;             // fully above diagonal: no work (uniform exit)

  __shared__ short lds[3][12288];   // 3 x 24KB

  const int qlo = 256 * p + 32 * w;   // batch-local base q row of this wave
  const int kb0 = 256 * s;            // batch-local first key of this split

  const short* qbh = q_hi + (size_t)(b * 2048 + qlo + col) * 64 + g * 8;
  const short* qbl = q_lo + (size_t)(b * 2048 + qlo + col) * 64 + g * 8;
  s16x8 qh0a = *(const s16x8*)(qbh);
  s16x8 qh1a = *(const s16x8*)(qbh + 32);
  s16x8 ql0a = *(const s16x8*)(qbl);
  s16x8 ql1a = *(const s16x8*)(qbl + 32);
  s16x8 qh0b = *(const s16x8*)(qbh + 16 * 64);
  s16x8 qh1b = *(const s16x8*)(qbh + 16 * 64 + 32);
  s16x8 ql0b = *(const s16x8*)(qbl + 16 * 64);
  s16x8 ql1b = *(const s16x8*)(qbl + 16 * 64 + 32);
  asm volatile("s_waitcnt vmcnt(0)" ::: "memory");
  __builtin_amdgcn_sched_barrier(0);

  f32x4 oA0 = {0,0,0,0}, oA1 = {0,0,0,0}, oA2 = {0,0,0,0}, oA3 = {0,0,0,0};
  f32x4 oB0 = {0,0,0,0}, oB1 = {0,0,0,0}, oB2 = {0,0,0,0}, oB3 = {0,0,0,0};
  float mA = -3.0e38f, lA = 0.0f, mB = -3.0e38f, lB = 0.0f;
  const f32x4 NEGV = {-3.0e38f, -3.0e38f, -3.0e38f, -3.0e38f};

#define STAGE(BP, J) do { \
    const int kbs_ = kb0 + 64 * (J); \
    const int r_ = 8 * w + (lane >> 3); \
    const int lc_ = (lane & 7) ^ (lane >> 3); \
    gl_lds16(k_hi + (size_t)(b * 2048 + kbs_ + r_) * 64 + lc_ * 8, (BP) + 8 * w * 64); \
    gl_lds16(k_lo + (size_t)(b * 2048 + kbs_ + r_) * 64 + lc_ * 8, (BP) + 4096 + 8 * w * 64); \
    gl_lds16(v_t + ((size_t)b * 64 + r_) * 2048 + kbs_ + lc_ * 8, (BP) + 8192 + 8 * w * 64); \
  } while (0)

#define PIPE_WAIT(N) do { \
    asm volatile("s_waitcnt vmcnt(" #N ")" ::: "memory"); \
    __builtin_amdgcn_s_barrier(); \
    __builtin_amdgcn_sched_barrier(0); \
  } while (0)
#define PIPE_END do { \
    asm volatile("s_waitcnt lgkmcnt(0)" ::: "memory"); \
    __builtin_amdgcn_sched_barrier(0); \
    __builtin_amdgcn_s_barrier(); \
  } while (0)

#define QK_U(U) do { \
    const int kg0_ = kb_ + 16 * U; \
    if (kg0_ <= qlo + 31) { \
      const short* kr_ = bp_ + (16 * U + col) * 64; \
      const int cx_ = col & 7; \
      s16x8 kh0_ = *(const s16x8*)(kr_ + ((g ^ cx_) << 3)); \
      s16x8 kh1_ = *(const s16x8*)(kr_ + (((4 + g) ^ cx_) << 3)); \
      s16x8 kl0_ = *(const s16x8*)(kr_ + 4096 + ((g ^ cx_) << 3)); \
      s16x8 kl1_ = *(const s16x8*)(kr_ + 4096 + (((4 + g) ^ cx_) << 3)); \
      if (kg0_ <= qlo + 15) { \
        f32x4 u1_ = {0,0,0,0}, u2_ = {0,0,0,0}; \
        u1_ = mfma32(kh0_, qh0a, u1_); u1_ = mfma32(kh1_, qh1a, u1_); \
        u2_ = mfma32(kh0_, ql0a, u2_); u2_ = mfma32(kh1_, ql1a, u2_); \
        u2_ = mfma32(kl0_, qh0a, u2_); u2_ = mfma32(kl1_, qh1a, u2_); \
        scA##U = u1_ + u2_; \
        if (kg0_ == qlo) { \
          _Pragma("unroll") for (int i = 0; i < 4; ++i) \
            if (4 * g + i > col) scA##U[i] = -3.0e38f; \
        } \
      } \
      { \
        f32x4 u1_ = {0,0,0,0}, u2_ = {0,0,0,0}; \
        u1_ = mfma32(kh0_, qh0b, u1_); u1_ = mfma32(kh1_, qh1b, u1_); \
        u2_ = mfma32(kh0_, ql0b, u2_); u2_ = mfma32(kh1_, ql1b, u2_); \
        u2_ = mfma32(kl0_, qh0b, u2_); u2_ = mfma32(kl1_, qh1b, u2_); \
        scB##U = u1_ + u2_; \
        if (kg0_ == qlo + 16) { \
          _Pragma("unroll") for (int i = 0; i < 4; ++i) \
            if (4 * g + i > col) scB##U[i] = -3.0e38f; \
        } \
      } \
    } \
  } while (0)

#define SMAX4(v) fmaxf(fmaxf((v)[0], (v)[1]), fmaxf((v)[2], (v)[3]))

#define SOFTMAX_X(s0v, s1v, s2v, s3v, mX, lX, o0X, o1X, o2X, o3X, p0X, p1X, p2X, p3X) do { \
    float mx_ = fmaxf(fmaxf(SMAX4(s0v), SMAX4(s1v)), fmaxf(SMAX4(s2v), SMAX4(s3v))); \
    mx_ = fmaxf(mx_, __shfl_xor(mx_, 16)); \
    mx_ = fmaxf(mx_, __shfl_xor(mx_, 32)); \
    const float mn_ = fmaxf(mX, mx_); \
    const float rs_ = __builtin_amdgcn_exp2f((mX - mn_) * LOG2E); \
    float ls_ = 0.f; \
    _Pragma("unroll") for (int i = 0; i < 4; ++i) { \
      float e0_ = __builtin_amdgcn_exp2f((s0v[i] - mn_) * LOG2E); \
      float e1_ = __builtin_amdgcn_exp2f((s1v[i] - mn_) * LOG2E); \
      float e2_ = __builtin_amdgcn_exp2f((s2v[i] - mn_) * LOG2E); \
      float e3_ = __builtin_amdgcn_exp2f((s3v[i] - mn_) * LOG2E); \
      p0X[i] = f2bf(e0_); p1X[i] = f2bf(e1_); p2X[i] = f2bf(e2_); p3X[i] = f2bf(e3_); \
      ls_ += e0_ + e1_ + e2_ + e3_; \
    } \
    lX = lX * rs_ + ls_; \
    o0X *= rs_; o1X *= rs_; o2X *= rs_; o3X *= rs_; \
    mX = mn_; \
  } while (0)

#define PV_U(U) do { \
    const int kg0_ = kb_ + 16 * U; \
    if (kg0_ <= qlo + 31) { \
      const int cx_ = col & 7; \
      const short* vr_ = bp_ + 8192 + col * 64 + ((g & 1) << 2) + \
                         (((2 * U + (g >> 1)) ^ cx_) << 3); \
      s16x4 v0_ = *(const s16x4*)(vr_); \
      s16x4 v1_ = *(const s16x4*)(vr_ + 1024); \
      s16x4 v2_ = *(const s16x4*)(vr_ + 2048); \
      s16x4 v3_ = *(const s16x4*)(vr_ + 3072); \
      if (kg0_ <= qlo + 15) { \
        oA0 = mfma16(v0_, pbA##U, oA0); \
        oA1 = mfma16(v1_, pbA##U, oA1); \
        oA2 = mfma16(v2_, pbA##U, oA2); \
        oA3 = mfma16(v3_, pbA##U, oA3); \
      } \
      oB0 = mfma16(v0_, pbB##U, oB0); \
      oB1 = mfma16(v1_, pbB##U, oB1); \
      oB2 = mfma16(v2_, pbB##U, oB2); \
      oB3 = mfma16(v3_, pbB##U, oB3); \
    } \
  } while (0)

#define COMPUTE(BP, J) do { \
    const int kb_ = kb0 + 64 * (J); \
    if (kb_ <= qlo + 31) { \
      const short* bp_ = (BP); \
      f32x4 scA0 = NEGV, scA1 = NEGV, scA2 = NEGV, scA3 = NEGV; \
      f32x4 scB0 = NEGV, scB1 = NEGV, scB2 = NEGV, scB3 = NEGV; \
      QK_U(0); QK_U(1); QK_U(2); QK_U(3); \
      s16x4 pbA0, pbA1, pbA2, pbA3, pbB0, pbB1, pbB2, pbB3; \
      if (kb_ <= qlo + 15) \
        SOFTMAX_X(scA0, scA1, scA2, scA3, mA, lA, oA0, oA1, oA2, oA3, \
                  pbA0, pbA1, pbA2, pbA3); \
      SOFTMAX_X(scB0, scB1, scB2, scB3, mB, lB, oB0, oB1, oB2, oB3, \
                pbB0, pbB1, pbB2, pbB3); \
      PV_U(0); PV_U(1); PV_U(2); PV_U(3); \
    } \
  } while (0)

  short* L0 = &lds[0][0];
  short* L1 = &lds[1][0];
  short* L2 = &lds[2][0];

  STAGE(L0, 0); STAGE(L1, 1);
  STAGE(L2, 2); PIPE_WAIT(6); COMPUTE(L0, 0); PIPE_END;
  STAGE(L0, 3); PIPE_WAIT(6); COMPUTE(L1, 1); PIPE_END;
  PIPE_WAIT(3); COMPUTE(L2, 2); PIPE_END;
  PIPE_WAIT(0); COMPUTE(L0, 3);

  lA += __shfl_xor(lA, 16); lA += __shfl_xor(lA, 32);
  lB += __shfl_xor(lB, 16); lB += __shfl_xor(lB, 32);
  const int rowA = b * 2048 + qlo + col;
  const int rowB = rowA + 16;
  if (g == 0) {
    pm[s * 8192 + rowA] = mA;  pl[s * 8192 + rowA] = lA;
    pm[s * 8192 + rowB] = mB;  pl[s * 8192 + rowB] = lB;
  }
  {
    float* dA = pO + ((size_t)s * 8192 + rowA) * 64 + 4 * g;
    float* dB = pO + ((size_t)s * 8192 + rowB) * 64 + 4 * g;
    *(f32x4*)(dA)      = oA0; *(f32x4*)(dA + 16) = oA1;
    *(f32x4*)(dA + 32) = oA2; *(f32x4*)(dA + 48) = oA3;
    *(f32x4*)(dB)      = oB0; *(f32x4*)(dB + 16) = oB1;
    *(f32x4*)(dB + 32) = oB2; *(f32x4*)(dB + 48) = oB3;
  }
#undef STAGE
#undef PIPE_WAIT
#undef PIPE_END
#undef QK_U
#undef SMAX4
#undef SOFTMAX_X
#undef PV_U
#undef COMPUTE
}

// ============================================================
// Kernel 3: combine split-K partials (UNCHANGED R5).
// ============================================================
__global__ __launch_bounds__(256) void reduce_p(
    const float* __restrict__ pm, const float* __restrict__ pl,
    const float* __restrict__ pO, float* __restrict__ out) {
  const int idx = blockIdx.x * 256 + threadIdx.x;   // 131072
  const int row = idx >> 4;
  const int hq = (idx & 15) * 4;
  const int smax = (row & 2047) >> 8;
  float M = -3.0e38f;
  for (int s = 0; s <= smax; ++s) M = fmaxf(M, pm[s * 8192 + row]);
  float L = 0.f;
  f32x4 acc = {0, 0, 0, 0};
  for (int s = 0; s <= smax; ++s) {
    const float ws = __builtin_amdgcn_exp2f((pm[s * 8192 + row] - M) * LOG2E);
    L += ws * pl[s * 8192 + row];
    f32x4 ov = *(const f32x4*)(pO + ((size_t)s * 8192 + row) * 64 + hq);
    acc += ov * ws;
  }
  const float invL = 1.0f / L;
  *(f32x4*)(out + (size_t)row * 64 + hq) = acc * invL;
}

// ============================================================
extern "C" void kernel_launch(void* const* d_in, const int* in_sizes, int n_in,
                              void* d_out, int out_size, void* d_ws, size_t ws_size,
                              hipStream_t stream) {
  const float* x  = (const float*)d_in[0];
  const float* Wq = (const float*)d_in[1];
  const float* bq = (const float*)d_in[2];
  const float* Wk = (const float*)d_in[3];
  const float* bk = (const float*)d_in[4];
  const float* Wv = (const float*)d_in[5];
  const float* bv = (const float*)d_in[6];
  float* out = (float*)d_out;

  char* ws = (char*)d_ws;
  short* wt_hi = (short*)(ws);                       // 192*1024*2 = 393216 B
  short* wt_lo = (short*)(ws + 393216);
  short* q_hi  = (short*)(ws + 786432);              // 8192*64*2 = 1 MiB each
  short* q_lo  = (short*)(ws + 786432 + 1048576);
  short* k_hi  = (short*)(ws + 786432 + 2 * 1048576);
  short* k_lo  = (short*)(ws + 786432 + 3 * 1048576);
  short* v_t   = (short*)(ws + 786432 + 4 * 1048576);  // end: 6,029,312 B
  float* pm    = (float*)(ws + 6029312);               // 8*8192*4 = 262144 B
  float* pl    = (float*)(ws + 6291456);               // 262144 B
  float* pO    = (float*)(ws + 6553600);               // 8*8192*64*4 = 16 MiB

  hipLaunchKernelGGL(prep_w, dim3(768), dim3(256), 0, stream, Wq, Wk, Wv, wt_hi, wt_lo);
  hipLaunchKernelGGL(proj_qkv, dim3(256), dim3(512), 0, stream,
                     x, wt_hi, wt_lo, bq, bk, bv, q_hi, q_lo, k_hi, k_lo, v_t);
  hipLaunchKernelGGL(attn, dim3(256), dim3(512), 0, stream,
                     q_hi, q_lo, k_hi, k_lo, v_t, pm, pl, pO);
  hipLaunchKernelGGL(reduce_p, dim3(512), dim3(256), 0, stream, pm, pl, pO, out);
}